// Round 5
// baseline (735.317 us; speedup 1.0000x reference)
//
#include <hip/hip_runtime.h>

#define BIGF 3.402823466e38f

typedef __attribute__((ext_vector_type(8))) short bf16x8;
typedef __attribute__((ext_vector_type(4))) float f32x4;

__device__ __forceinline__ void gload_lds16u(const unsigned short* g, unsigned short* lds) {
  __builtin_amdgcn_global_load_lds((const __attribute__((address_space(1))) void*)g,
                                   (__attribute__((address_space(3))) void*)lds, 16, 0, 0);
}

__device__ __forceinline__ unsigned short bf16_rne(float f) {
  unsigned int u = __float_as_uint(f);
  return (unsigned short)((u + 0x7fffu + ((u >> 16) & 1u)) >> 16);
}

// ---------------- K1: transpose + sq + y + delta + bf16 hi/lo packed rows ----------------
__global__ __launch_bounds__(256) void k1_pre(const float* __restrict__ x, const float* __restrict__ w,
                                              float* __restrict__ sq, float* __restrict__ y,
                                              float* __restrict__ delta, unsigned short* __restrict__ xhl) {
  __shared__ __align__(16) float xt[64][68];
  __shared__ __align__(16) float ws[128][64];
  const int t = threadIdx.x;
  const int bid = blockIdx.x;
  const int b = bid >> 6;
  const int n0 = (bid & 63) << 6;
  const float* xb = x + (size_t)b * 64 * 4096;

#pragma unroll
  for (int rep = 0; rep < 16; ++rep) {
    int id = rep * 256 + t;
    int d = id >> 6, n = id & 63;
    xt[n][d] = xb[(size_t)d * 4096 + n0 + n];
  }
#pragma unroll
  for (int rep = 0; rep < 32; ++rep) {
    int id = rep * 256 + t;
    int u = id >> 6, dd = id & 63;
    ws[u][dd] = w[(u & 63) * 128 + ((u >> 6) << 6) + dd];
  }
  __syncthreads();

  {
    const int p = t >> 2;
    const int cg = t & 3;
    uint4* orow = (uint4*)xhl + ((size_t)(b << 12) + n0 + p) * 16;
#pragma unroll
    for (int cc = 0; cc < 4; ++cc) {
      const int c = cg * 4 + cc;
      const int kb = (c & 7) * 8;
      const bool lohalf = (c >= 8);
      unsigned int pk[4];
#pragma unroll
      for (int j2 = 0; j2 < 4; ++j2) {
        unsigned short u0, u1;
#pragma unroll
        for (int e = 0; e < 2; ++e) {
          const float xv = xt[p][kb + j2 * 2 + e];
          unsigned short h = bf16_rne(xv);
          unsigned short r;
          if (!lohalf) r = h;
          else r = bf16_rne(xv - __uint_as_float(((unsigned int)h) << 16));
          if (e == 0) u0 = r; else u1 = r;
        }
        pk[j2] = (unsigned int)u0 | ((unsigned int)u1 << 16);
      }
      uint4 v;
      v.x = pk[0]; v.y = pk[1]; v.z = pk[2]; v.w = pk[3];
      orow[c ^ (p & 7)] = v;
    }
  }

  const int p = t & 63;
  const int oc = t >> 6;
  float accy[16], accz[16];
#pragma unroll
  for (int j = 0; j < 16; ++j) { accy[j] = 0.f; accz[j] = 0.f; }

#pragma unroll 4
  for (int d4 = 0; d4 < 16; ++d4) {
    const float4 xv = *(const float4*)&xt[p][d4 * 4];
#pragma unroll
    for (int j = 0; j < 16; ++j) {
      const int o = oc * 16 + j;
      const float4 wy = *(const float4*)&ws[o][d4 * 4];
      const float4 wz = *(const float4*)&ws[o + 64][d4 * 4];
      accy[j] = fmaf(xv.x, wy.x, fmaf(xv.y, wy.y, fmaf(xv.z, wy.z, fmaf(xv.w, wy.w, accy[j]))));
      accz[j] = fmaf(xv.x, wz.x, fmaf(xv.y, wz.y, fmaf(xv.z, wz.z, fmaf(xv.w, wz.w, accz[j]))));
    }
  }

  if (oc == 0) {
    float s = 0.f;
#pragma unroll
    for (int d4 = 0; d4 < 16; ++d4) {
      const float4 v = *(const float4*)&xt[p][d4 * 4];
      s = fmaf(v.x, v.x, fmaf(v.y, v.y, fmaf(v.z, v.z, fmaf(v.w, v.w, s))));
    }
    sq[b * 4096 + n0 + p] = s;
  }

  const size_t row = ((size_t)b * 4096 + n0 + p) * 64 + oc * 16;
#pragma unroll
  for (int j4 = 0; j4 < 4; ++j4) {
    float4 yv = make_float4(accy[j4 * 4], accy[j4 * 4 + 1], accy[j4 * 4 + 2], accy[j4 * 4 + 3]);
    float4 dv = make_float4(accz[j4 * 4] - accy[j4 * 4], accz[j4 * 4 + 1] - accy[j4 * 4 + 1],
                            accz[j4 * 4 + 2] - accy[j4 * 4 + 2], accz[j4 * 4 + 3] - accy[j4 * 4 + 3]);
    *(float4*)&y[row + j4 * 4] = yv;
    *(float4*)&delta[row + j4 * 4] = dv;
  }
}

// ---------------- K2: MFMA distance GEMM (bf16 hi/lo) + streaming top-20 ----------------
// Round-3 skeleton (m-tile 32, single-buffer) + push-time threshold tightening:
// after c pushes since last drain, 20th-smallest <= max(kd[19-min(c,4)], max_pushed).
__global__ __launch_bounds__(256, 2) void k2_knn(const unsigned short* __restrict__ xhl,
                                                 const float* __restrict__ sq,
                                                 int* __restrict__ idx_out) {
  __shared__ __align__(16) float smem[4096 + 8192 + 6656];
  const int t = threadIdx.x;
  const int lane = t & 63;
  const int w = t >> 6;
  float* BsW = smem + 4096 + (w << 11);
  uint2* bufL = (uint2*)(smem + 12288) + ((w << 6) + lane) * 13;

  const int bid = blockIdx.x;
  const int b = bid >> 6;
  const int n0 = (bid & 63) << 6;
  const int pn = lane & 15, q = lane >> 4;

  const unsigned short* xr = xhl + ((size_t)(b << 12)) * 128;
  const float* sqb = sq + (b << 12);

  // stage A rows (64 points x 256B = 16KB): 16 x 1KB, 4 per wave
  {
    unsigned short* asu = (unsigned short*)smem;
#pragma unroll
    for (int qq = 0; qq < 4; ++qq) {
      const int kk = w * 4 + qq;
      gload_lds16u(xr + (size_t)n0 * 128 + kk * 512 + lane * 8, asu + kk * 512);
    }
  }
  __syncthreads();

  // n-side fragments, register-resident: per nt: [hi0, hi1, lo0, lo1]
  bf16x8 bfr[4][4];
  {
    const uint4* As4 = (const uint4*)smem;
#pragma unroll
    for (int nt = 0; nt < 4; ++nt)
#pragma unroll
      for (int j = 0; j < 4; ++j)
        bfr[nt][j] = *reinterpret_cast<const bf16x8*>(&As4[((nt << 4) + pn) * 16 + (((j << 2) + q) ^ (pn & 7))]);
  }

  float kd[20];
  int ki[20];
#pragma unroll
  for (int s = 0; s < 20; ++s) { kd[s] = BIGF; ki[s] = -1; }
  const float sqn = sqb[n0 + lane];
  const int myn = lane;
  const int swz = myn & 7;
  int cnt = 0;

  // threshold state: tau (d2-space), taup = tau - sqn (raw-v space), push-time bound
  float tau = BIGF, taup = BIGF, mp = -BIGF;
  float k15 = BIGF, k16 = BIGF, k17 = BIGF, k18 = BIGF;

  auto ins = [&](float vd, int vi) {
#pragma unroll
    for (int s = 0; s < 20; ++s) {
      const float od = kd[s];
      const int oi = ki[s];
      const bool lt = vd < od;
      kd[s] = lt ? vd : od;
      ki[s] = lt ? vi : oi;
      vd = lt ? od : vd;
      vi = lt ? oi : vi;
    }
  };

  auto drain = [&]() {
#pragma unroll 1
    for (int j = 0; j < 12; ++j) {
      if (!__any(j < cnt)) break;
      if (j < cnt) {
        const uint2 e = bufL[j];
        const float dv = __uint_as_float(e.x);
        if (dv < kd[19]) ins(dv, (int)e.y);
      }
    }
    cnt = 0;
    tau = kd[19];
    taup = tau - sqn;
    mp = -BIGF;
    k15 = kd[15]; k16 = kd[16]; k17 = kd[17]; k18 = kd[18];
  };

  auto push = [&](float rawv, int mi) {
    const float d2 = sqn + rawv;
    bufL[cnt] = make_uint2(__float_as_uint(d2), (unsigned)mi);
    ++cnt;
    mp = fmaxf(mp, d2);
    const float bnd = (cnt >= 4) ? k15 : ((cnt == 3) ? k16 : ((cnt == 2) ? k17 : k18));
    tau = fminf(tau, fmaxf(bnd, mp));
    taup = tau - sqn;
  };

  const f32x4 zero4 = {0.f, 0.f, 0.f, 0.f};
  f32x4 acc[4][2];
#pragma unroll
  for (int nt = 0; nt < 4; ++nt) { acc[nt][0] = zero4; acc[nt][1] = zero4; }

  for (int kt = 0; kt < 32; ++kt) {
    const int mbase = (w + 4 * kt) << 5;
    // stage m rows (32 points x 256B = 8KB): 8 x 1KB
    {
      unsigned short* bsu = (unsigned short*)BsW;
      const unsigned short* src = xr + (size_t)mbase * 128;
#pragma unroll
      for (int k = 0; k < 8; ++k) gload_lds16u(src + k * 512 + lane * 8, bsu + k * 512);
    }
    const f32x4 sqm0 = *(const f32x4*)&sqb[mbase + (q << 2)];
    const f32x4 sqm1 = *(const f32x4*)&sqb[mbase + 16 + (q << 2)];
    __builtin_amdgcn_s_waitcnt(0x0F70);  // vmcnt(0)

#pragma unroll
    for (int mt = 0; mt < 2; ++mt) {
      bf16x8 afr[4];
#pragma unroll
      for (int j = 0; j < 4; ++j)
        afr[j] = *reinterpret_cast<const bf16x8*>(&((const uint4*)BsW)[((mt << 4) + pn) * 16 + (((j << 2) + q) ^ (pn & 7))]);
#pragma unroll
      for (int nt = 0; nt < 4; ++nt) {
        f32x4 a = acc[nt][mt];
        a = __builtin_amdgcn_mfma_f32_16x16x32_bf16(afr[0], bfr[nt][0], a, 0, 0, 0);  // hi_m*hi_n
        a = __builtin_amdgcn_mfma_f32_16x16x32_bf16(afr[1], bfr[nt][1], a, 0, 0, 0);
        a = __builtin_amdgcn_mfma_f32_16x16x32_bf16(afr[0], bfr[nt][2], a, 0, 0, 0);  // hi_m*lo_n
        a = __builtin_amdgcn_mfma_f32_16x16x32_bf16(afr[1], bfr[nt][3], a, 0, 0, 0);
        a = __builtin_amdgcn_mfma_f32_16x16x32_bf16(afr[2], bfr[nt][0], a, 0, 0, 0);  // lo_m*hi_n
        a = __builtin_amdgcn_mfma_f32_16x16x32_bf16(afr[3], bfr[nt][1], a, 0, 0, 0);
        acc[nt][mt] = a;
      }
    }

    // dump: value = sq_m - 2*dot, row n, m-quad g=(mt*4+q) at chunk g^(n&7)
#pragma unroll
    for (int nt = 0; nt < 4; ++nt) {
#pragma unroll
      for (int mt = 0; mt < 2; ++mt) {
        const int n = (nt << 4) + pn;
        const int g = (mt << 2) + q;
        const int pc = g ^ (n & 7);
        const f32x4 sv = mt ? sqm1 : sqm0;
        f32x4 dv = sv - 2.0f * acc[nt][mt];
        *(f32x4*)&BsW[(n << 5) + (pc << 2)] = dv;
        acc[nt][mt] = zero4;
      }
    }

    // scan own row (myn): raw-v compares vs taup; push tightens tau
#pragma unroll 1
    for (int cc = 0; cc < 8; ++cc) {
      const float4 v = *(const float4*)&BsW[(myn << 5) + ((cc ^ swz) << 2)];
      const int mb = mbase + (cc << 2);
      const float mn = fminf(fminf(v.x, v.y), fminf(v.z, v.w));
      if (mn < taup) {
        if (v.x < taup) push(v.x, mb);
        if (v.y < taup) push(v.y, mb + 1);
        if (v.z < taup) push(v.z, mb + 2);
        if (v.w < taup) push(v.w, mb + 3);
      }
      if (__any(cnt > 8)) drain();
    }
  }
  drain();

  // merge the 4 waves' partial lists (LDS overlay on smem)
  __syncthreads();
  float* pf = smem;                 // [4][20][64]
  int* pi = (int*)(smem + 5120);    // [4][20][64]
#pragma unroll
  for (int s = 0; s < 20; ++s) {
    pf[(w * 20 + s) * 64 + lane] = kd[s];
    pi[(w * 20 + s) * 64 + lane] = ki[s];
  }
  __syncthreads();
  if (w == 0) {
    auto insTie = [&](float vd, int vi) {
#pragma unroll
      for (int s = 0; s < 20; ++s) {
        const float od = kd[s];
        const int oi = ki[s];
        const bool lt = (vd < od) || (vd == od && vi < oi);
        kd[s] = lt ? vd : od;
        ki[s] = lt ? vi : oi;
        vd = lt ? od : vd;
        vi = lt ? oi : vi;
      }
    };
    for (int ww = 1; ww < 4; ++ww) {
#pragma unroll 1
      for (int s = 0; s < 20; ++s) {
        const float dv = pf[(ww * 20 + s) * 64 + lane];
        const int iv = pi[(ww * 20 + s) * 64 + lane];
        if (dv < kd[19] || (dv == kd[19] && iv < ki[19])) insTie(dv, iv);
      }
    }
    int* orow = idx_out + ((size_t)(b << 12) + n0 + lane) * 20;
#pragma unroll
    for (int s = 0; s < 20; ++s) orow[s] = ki[s];
  }
}

// ---------------- K3: gathered neighbor max (float4) + h + BN stats ----------------
__global__ __launch_bounds__(256) void k3_gather(const float* __restrict__ y,
                                                 const float* __restrict__ delta,
                                                 const int* __restrict__ idx,
                                                 float* __restrict__ h,
                                                 float* __restrict__ sums,
                                                 float* __restrict__ sumsq) {
  __shared__ float r1[16][64], r2[16][64];
  const int t = threadIdx.x;
  const int cg = t & 15;   // channels 4cg..4cg+3
  const int pw = t >> 4;   // 16 point-slots
  const int blk = blockIdx.x;  // 1024 blocks x 32 points
  float4 s1 = make_float4(0.f, 0.f, 0.f, 0.f), s2 = s1;
#pragma unroll 1
  for (int pp = 0; pp < 2; ++pp) {
    const int ng = blk * 32 + pp * 16 + pw;
    const int b = ng >> 12;
    const int* row = idx + (size_t)ng * 20;
    float4 mx = make_float4(-BIGF, -BIGF, -BIGF, -BIGF);
#pragma unroll
    for (int kk = 0; kk < 20; ++kk) {
      const int nbr = row[kk];
      const float4 v = *(const float4*)&y[(((size_t)(b << 12)) + nbr) * 64 + cg * 4];
      mx.x = fmaxf(mx.x, v.x); mx.y = fmaxf(mx.y, v.y);
      mx.z = fmaxf(mx.z, v.z); mx.w = fmaxf(mx.w, v.w);
    }
    const float4 dl = *(const float4*)&delta[(size_t)ng * 64 + cg * 4];
    float4 hv = make_float4(mx.x + dl.x, mx.y + dl.y, mx.z + dl.z, mx.w + dl.w);
    *(float4*)&h[(size_t)ng * 64 + cg * 4] = hv;
    s1.x += hv.x; s1.y += hv.y; s1.z += hv.z; s1.w += hv.w;
    s2.x += hv.x * hv.x; s2.y += hv.y * hv.y; s2.z += hv.z * hv.z; s2.w += hv.w * hv.w;
  }
  *(float4*)&r1[pw][cg * 4] = s1;
  *(float4*)&r2[pw][cg * 4] = s2;
  __syncthreads();
  if (t < 64) {
    float a = 0.f, c = 0.f;
#pragma unroll
    for (int i = 0; i < 16; ++i) { a += r1[i][t]; c += r2[i][t]; }
    atomicAdd(&sums[t], a);
    atomicAdd(&sumsq[t], c);
  }
}

// ---------------- K4: BN finalize + exact GELU + transposed write ----------------
__global__ __launch_bounds__(256) void k4_bn(const float* __restrict__ h,
                                             const float* __restrict__ sums,
                                             const float* __restrict__ sumsq,
                                             const float* __restrict__ gamma,
                                             const float* __restrict__ beta,
                                             float* __restrict__ out) {
  __shared__ float tile[64][65];
  const int bid = blockIdx.x;
  const int b = bid >> 6;
  const int n0 = (bid & 63) << 6;
  const int t = threadIdx.x;
  const int o = t & 63;
#pragma unroll
  for (int it = 0; it < 16; ++it) {
    const int n = (t >> 6) * 16 + it;
    tile[n][o] = h[(((size_t)b << 12) + n0 + n) * 64 + o];
  }
  __syncthreads();
  const int j = t & 63;
#pragma unroll
  for (int it = 0; it < 16; ++it) {
    const int oo = (t >> 6) * 16 + it;
    const float mean = sums[oo] * (1.0f / 32768.0f);
    const float var = sumsq[oo] * (1.0f / 32768.0f) - mean * mean;
    const float sc = gamma[oo] / sqrtf(var + 1e-5f);
    const float hv = tile[j][oo];
    const float hn = (hv - mean) * sc + beta[oo];
    const float g = 0.5f * hn * (1.0f + erff(hn * 0.70710678118654752f));
    out[((size_t)(b * 64 + oo)) * 4096 + n0 + j] = g;
  }
}

extern "C" void kernel_launch(void* const* d_in, const int* in_sizes, int n_in,
                              void* d_out, int out_size, void* d_ws, size_t ws_size,
                              hipStream_t stream) {
  const float* x = (const float*)d_in[0];
  const float* w = (const float*)d_in[1];
  const float* gamma = (const float*)d_in[2];
  const float* beta = (const float*)d_in[3];
  float* out = (float*)d_out;

  float* sq_ws = (float*)d_ws;               // 32768
  float* y_ws = sq_ws + 32768;               // 8 MB
  float* delta_ws = y_ws + 2097152;          // 8 MB
  float* h_ws = delta_ws + 2097152;          // 8 MB (k3/k4) — overlaid by xhl in k1/k2
  int* idx_ws = (int*)(h_ws + 2097152);      // 2.6 MB
  float* sums = (float*)(idx_ws + 655360);   // 64
  float* sumsq = sums + 64;                  // 64
  unsigned short* xhl = (unsigned short*)h_ws;  // 8 MB bf16 hi/lo rows (dead after k2)

  hipMemsetAsync(sums, 0, 2 * 64 * sizeof(float), stream);
  k1_pre<<<512, 256, 0, stream>>>(x, w, sq_ws, y_ws, delta_ws, xhl);
  k2_knn<<<512, 256, 0, stream>>>(xhl, sq_ws, idx_ws);
  k3_gather<<<1024, 256, 0, stream>>>(y_ws, delta_ws, idx_ws, h_ws, sums, sumsq);
  k4_bn<<<512, 256, 0, stream>>>(h_ws, sums, sumsq, gamma, beta, out);
}

// Round 6
// 376.129 us; speedup vs baseline: 1.9550x; 1.9550x over previous
//
#include <hip/hip_runtime.h>

#define BIGF 3.402823466e38f

typedef __attribute__((ext_vector_type(8))) short bf16x8;
typedef __attribute__((ext_vector_type(4))) float f32x4;

__device__ __forceinline__ void gload_lds16u(const unsigned short* g, unsigned short* lds) {
  __builtin_amdgcn_global_load_lds((const __attribute__((address_space(1))) void*)g,
                                   (__attribute__((address_space(3))) void*)lds, 16, 0, 0);
}

__device__ __forceinline__ unsigned short bf16_rne(float f) {
  unsigned int u = __float_as_uint(f);
  return (unsigned short)((u + 0x7fffu + ((u >> 16) & 1u)) >> 16);
}

// ---------------- K1: transpose + sq + y + delta + bf16 hi/lo packed rows ----------------
__global__ __launch_bounds__(256) void k1_pre(const float* __restrict__ x, const float* __restrict__ w,
                                              float* __restrict__ sq, float* __restrict__ y,
                                              float* __restrict__ delta, unsigned short* __restrict__ xhl) {
  __shared__ __align__(16) float xt[64][68];
  __shared__ __align__(16) float ws[128][64];
  const int t = threadIdx.x;
  const int bid = blockIdx.x;
  const int b = bid >> 6;
  const int n0 = (bid & 63) << 6;
  const float* xb = x + (size_t)b * 64 * 4096;

#pragma unroll
  for (int rep = 0; rep < 16; ++rep) {
    int id = rep * 256 + t;
    int d = id >> 6, n = id & 63;
    xt[n][d] = xb[(size_t)d * 4096 + n0 + n];
  }
#pragma unroll
  for (int rep = 0; rep < 32; ++rep) {
    int id = rep * 256 + t;
    int u = id >> 6, dd = id & 63;
    ws[u][dd] = w[(u & 63) * 128 + ((u >> 6) << 6) + dd];
  }
  __syncthreads();

  {
    const int p = t >> 2;
    const int cg = t & 3;
    uint4* orow = (uint4*)xhl + ((size_t)(b << 12) + n0 + p) * 16;
#pragma unroll
    for (int cc = 0; cc < 4; ++cc) {
      const int c = cg * 4 + cc;
      const int kb = (c & 7) * 8;
      const bool lohalf = (c >= 8);
      unsigned int pk[4];
#pragma unroll
      for (int j2 = 0; j2 < 4; ++j2) {
        unsigned short u0, u1;
#pragma unroll
        for (int e = 0; e < 2; ++e) {
          const float xv = xt[p][kb + j2 * 2 + e];
          unsigned short h = bf16_rne(xv);
          unsigned short r;
          if (!lohalf) r = h;
          else r = bf16_rne(xv - __uint_as_float(((unsigned int)h) << 16));
          if (e == 0) u0 = r; else u1 = r;
        }
        pk[j2] = (unsigned int)u0 | ((unsigned int)u1 << 16);
      }
      uint4 v;
      v.x = pk[0]; v.y = pk[1]; v.z = pk[2]; v.w = pk[3];
      orow[c ^ (p & 7)] = v;
    }
  }

  const int p = t & 63;
  const int oc = t >> 6;
  float accy[16], accz[16];
#pragma unroll
  for (int j = 0; j < 16; ++j) { accy[j] = 0.f; accz[j] = 0.f; }

#pragma unroll 4
  for (int d4 = 0; d4 < 16; ++d4) {
    const float4 xv = *(const float4*)&xt[p][d4 * 4];
#pragma unroll
    for (int j = 0; j < 16; ++j) {
      const int o = oc * 16 + j;
      const float4 wy = *(const float4*)&ws[o][d4 * 4];
      const float4 wz = *(const float4*)&ws[o + 64][d4 * 4];
      accy[j] = fmaf(xv.x, wy.x, fmaf(xv.y, wy.y, fmaf(xv.z, wy.z, fmaf(xv.w, wy.w, accy[j]))));
      accz[j] = fmaf(xv.x, wz.x, fmaf(xv.y, wz.y, fmaf(xv.z, wz.z, fmaf(xv.w, wz.w, accz[j]))));
    }
  }

  if (oc == 0) {
    float s = 0.f;
#pragma unroll
    for (int d4 = 0; d4 < 16; ++d4) {
      const float4 v = *(const float4*)&xt[p][d4 * 4];
      s = fmaf(v.x, v.x, fmaf(v.y, v.y, fmaf(v.z, v.z, fmaf(v.w, v.w, s))));
    }
    sq[b * 4096 + n0 + p] = s;
  }

  const size_t row = ((size_t)b * 4096 + n0 + p) * 64 + oc * 16;
#pragma unroll
  for (int j4 = 0; j4 < 4; ++j4) {
    float4 yv = make_float4(accy[j4 * 4], accy[j4 * 4 + 1], accy[j4 * 4 + 2], accy[j4 * 4 + 3]);
    float4 dv = make_float4(accz[j4 * 4] - accy[j4 * 4], accz[j4 * 4 + 1] - accy[j4 * 4 + 1],
                            accz[j4 * 4 + 2] - accy[j4 * 4 + 2], accz[j4 * 4 + 3] - accy[j4 * 4 + 3]);
    *(float4*)&y[row + j4 * 4] = yv;
    *(float4*)&delta[row + j4 * 4] = dv;
  }
}

// ---------------- K2: MFMA distance GEMM (bf16 hi/lo) + streaming top-20 ----------------
// Round-3 skeleton, LDS shrunk to 51.2KB for 3 blocks/CU: B slices 4x8KB at [0..8191],
// accept buffers 9 uint2/lane at [8192..12799]; A-stage (4096f) overlays [0..4095] at init.
// Scan gate compares raw v vs taup = kd[19]-sqn (refreshed at drains only; no push state).
__global__ __launch_bounds__(256, 3) void k2_knn(const unsigned short* __restrict__ xhl,
                                                 const float* __restrict__ sq,
                                                 int* __restrict__ idx_out) {
  __shared__ __align__(16) float smem[12800];
  const int t = threadIdx.x;
  const int lane = t & 63;
  const int w = t >> 6;
  float* BsW = smem + (w << 11);
  uint2* bufL = (uint2*)(smem + 8192) + ((w << 6) + lane) * 9;

  const int bid = blockIdx.x;
  const int b = bid >> 6;
  const int n0 = (bid & 63) << 6;
  const int pn = lane & 15, q = lane >> 4;

  const unsigned short* xr = xhl + ((size_t)(b << 12)) * 128;
  const float* sqb = sq + (b << 12);

  // stage A rows (64 points x 256B = 16KB) into smem[0..4095]: 16 x 1KB, 4 per wave
  {
    unsigned short* asu = (unsigned short*)smem;
#pragma unroll
    for (int qq = 0; qq < 4; ++qq) {
      const int kk = w * 4 + qq;
      gload_lds16u(xr + (size_t)n0 * 128 + kk * 512 + lane * 8, asu + kk * 512);
    }
  }
  __syncthreads();

  // n-side fragments, register-resident: per nt: [hi0, hi1, lo0, lo1]
  bf16x8 bfr[4][4];
  {
    const uint4* As4 = (const uint4*)smem;
#pragma unroll
    for (int nt = 0; nt < 4; ++nt)
#pragma unroll
      for (int j = 0; j < 4; ++j)
        bfr[nt][j] = *reinterpret_cast<const bf16x8*>(&As4[((nt << 4) + pn) * 16 + (((j << 2) + q) ^ (pn & 7))]);
  }
  __syncthreads();  // all waves done reading As before slices overwrite it

  float kd[20];
  int ki[20];
#pragma unroll
  for (int s = 0; s < 20; ++s) { kd[s] = BIGF; ki[s] = -1; }
  const float sqn = sqb[n0 + lane];
  const int myn = lane;
  const int swz = myn & 7;
  int cnt = 0;
  float taup = BIGF;  // kd[19] - sqn, refreshed at drains

  auto ins = [&](float vd, int vi) {
#pragma unroll
    for (int s = 0; s < 20; ++s) {
      const float od = kd[s];
      const int oi = ki[s];
      const bool lt = vd < od;
      kd[s] = lt ? vd : od;
      ki[s] = lt ? vi : oi;
      vd = lt ? od : vd;
      vi = lt ? oi : vi;
    }
  };

  auto drain = [&]() {
#pragma unroll 1
    for (int j = 0; j < 8; ++j) {
      if (!__any(j < cnt)) break;
      if (j < cnt) {
        const uint2 e = bufL[j];
        const float dv = sqn + __uint_as_float(e.x);  // raw v -> d2
        if (dv < kd[19]) ins(dv, (int)e.y);
      }
    }
    cnt = 0;
    taup = kd[19] - sqn;
  };

  const f32x4 zero4 = {0.f, 0.f, 0.f, 0.f};
  f32x4 acc[4][2];
#pragma unroll
  for (int nt = 0; nt < 4; ++nt) { acc[nt][0] = zero4; acc[nt][1] = zero4; }

  for (int kt = 0; kt < 32; ++kt) {
    const int mbase = (w + 4 * kt) << 5;
    // stage m rows (32 points x 256B = 8KB): 8 x 1KB
    {
      unsigned short* bsu = (unsigned short*)BsW;
      const unsigned short* src = xr + (size_t)mbase * 128;
#pragma unroll
      for (int k = 0; k < 8; ++k) gload_lds16u(src + k * 512 + lane * 8, bsu + k * 512);
    }
    const f32x4 sqm0 = *(const f32x4*)&sqb[mbase + (q << 2)];
    const f32x4 sqm1 = *(const f32x4*)&sqb[mbase + 16 + (q << 2)];
    __builtin_amdgcn_s_waitcnt(0x0F70);  // vmcnt(0)

#pragma unroll
    for (int mt = 0; mt < 2; ++mt) {
      bf16x8 afr[4];
#pragma unroll
      for (int j = 0; j < 4; ++j)
        afr[j] = *reinterpret_cast<const bf16x8*>(&((const uint4*)BsW)[((mt << 4) + pn) * 16 + (((j << 2) + q) ^ (pn & 7))]);
#pragma unroll
      for (int nt = 0; nt < 4; ++nt) {
        f32x4 a = acc[nt][mt];
        a = __builtin_amdgcn_mfma_f32_16x16x32_bf16(afr[0], bfr[nt][0], a, 0, 0, 0);  // hi_m*hi_n
        a = __builtin_amdgcn_mfma_f32_16x16x32_bf16(afr[1], bfr[nt][1], a, 0, 0, 0);
        a = __builtin_amdgcn_mfma_f32_16x16x32_bf16(afr[0], bfr[nt][2], a, 0, 0, 0);  // hi_m*lo_n
        a = __builtin_amdgcn_mfma_f32_16x16x32_bf16(afr[1], bfr[nt][3], a, 0, 0, 0);
        a = __builtin_amdgcn_mfma_f32_16x16x32_bf16(afr[2], bfr[nt][0], a, 0, 0, 0);  // lo_m*hi_n
        a = __builtin_amdgcn_mfma_f32_16x16x32_bf16(afr[3], bfr[nt][1], a, 0, 0, 0);
        acc[nt][mt] = a;
      }
    }

    // dump: value = sq_m - 2*dot, row n, m-quad g=(mt*4+q) at chunk g^(n&7)
#pragma unroll
    for (int nt = 0; nt < 4; ++nt) {
#pragma unroll
      for (int mt = 0; mt < 2; ++mt) {
        const int n = (nt << 4) + pn;
        const int g = (mt << 2) + q;
        const int pc = g ^ (n & 7);
        const f32x4 sv = mt ? sqm1 : sqm0;
        f32x4 dv = sv - 2.0f * acc[nt][mt];
        *(f32x4*)&BsW[(n << 5) + (pc << 2)] = dv;
        acc[nt][mt] = zero4;
      }
    }

    // scan own row (myn): raw v vs taup; push stores raw v (no state updates)
#pragma unroll 1
    for (int cc = 0; cc < 8; ++cc) {
      const float4 v = *(const float4*)&BsW[(myn << 5) + ((cc ^ swz) << 2)];
      const int mb = mbase + (cc << 2);
      const float mn = fminf(fminf(v.x, v.y), fminf(v.z, v.w));
      if (mn < taup) {
        if (v.x < taup) { bufL[cnt] = make_uint2(__float_as_uint(v.x), (unsigned)mb); cnt++; }
        if (v.y < taup) { bufL[cnt] = make_uint2(__float_as_uint(v.y), (unsigned)(mb + 1)); cnt++; }
        if (v.z < taup) { bufL[cnt] = make_uint2(__float_as_uint(v.z), (unsigned)(mb + 2)); cnt++; }
        if (v.w < taup) { bufL[cnt] = make_uint2(__float_as_uint(v.w), (unsigned)(mb + 3)); cnt++; }
      }
      if (__any(cnt > 4)) drain();
    }
  }
  drain();

  // merge the 4 waves' partial lists (LDS overlay on smem)
  __syncthreads();
  float* pf = smem;                 // [4][20][64]
  int* pi = (int*)(smem + 5120);    // [4][20][64]
#pragma unroll
  for (int s = 0; s < 20; ++s) {
    pf[(w * 20 + s) * 64 + lane] = kd[s];
    pi[(w * 20 + s) * 64 + lane] = ki[s];
  }
  __syncthreads();
  if (w == 0) {
    auto insTie = [&](float vd, int vi) {
#pragma unroll
      for (int s = 0; s < 20; ++s) {
        const float od = kd[s];
        const int oi = ki[s];
        const bool lt = (vd < od) || (vd == od && vi < oi);
        kd[s] = lt ? vd : od;
        ki[s] = lt ? vi : oi;
        vd = lt ? od : vd;
        vi = lt ? oi : vi;
      }
    };
    for (int ww = 1; ww < 4; ++ww) {
#pragma unroll 1
      for (int s = 0; s < 20; ++s) {
        const float dv = pf[(ww * 20 + s) * 64 + lane];
        const int iv = pi[(ww * 20 + s) * 64 + lane];
        if (dv < kd[19] || (dv == kd[19] && iv < ki[19])) insTie(dv, iv);
      }
    }
    int* orow = idx_out + ((size_t)(b << 12) + n0 + lane) * 20;
#pragma unroll
    for (int s = 0; s < 20; ++s) orow[s] = ki[s];
  }
}

// ---------------- K3: gathered neighbor max (float4) + h + BN stats ----------------
__global__ __launch_bounds__(256) void k3_gather(const float* __restrict__ y,
                                                 const float* __restrict__ delta,
                                                 const int* __restrict__ idx,
                                                 float* __restrict__ h,
                                                 float* __restrict__ sums,
                                                 float* __restrict__ sumsq) {
  __shared__ float r1[16][64], r2[16][64];
  const int t = threadIdx.x;
  const int cg = t & 15;   // channels 4cg..4cg+3
  const int pw = t >> 4;   // 16 point-slots
  const int blk = blockIdx.x;  // 1024 blocks x 32 points
  float4 s1 = make_float4(0.f, 0.f, 0.f, 0.f), s2 = s1;
#pragma unroll 1
  for (int pp = 0; pp < 2; ++pp) {
    const int ng = blk * 32 + pp * 16 + pw;
    const int b = ng >> 12;
    const int* row = idx + (size_t)ng * 20;
    float4 mx = make_float4(-BIGF, -BIGF, -BIGF, -BIGF);
#pragma unroll
    for (int kk = 0; kk < 20; ++kk) {
      const int nbr = row[kk];
      const float4 v = *(const float4*)&y[(((size_t)(b << 12)) + nbr) * 64 + cg * 4];
      mx.x = fmaxf(mx.x, v.x); mx.y = fmaxf(mx.y, v.y);
      mx.z = fmaxf(mx.z, v.z); mx.w = fmaxf(mx.w, v.w);
    }
    const float4 dl = *(const float4*)&delta[(size_t)ng * 64 + cg * 4];
    float4 hv = make_float4(mx.x + dl.x, mx.y + dl.y, mx.z + dl.z, mx.w + dl.w);
    *(float4*)&h[(size_t)ng * 64 + cg * 4] = hv;
    s1.x += hv.x; s1.y += hv.y; s1.z += hv.z; s1.w += hv.w;
    s2.x += hv.x * hv.x; s2.y += hv.y * hv.y; s2.z += hv.z * hv.z; s2.w += hv.w * hv.w;
  }
  *(float4*)&r1[pw][cg * 4] = s1;
  *(float4*)&r2[pw][cg * 4] = s2;
  __syncthreads();
  if (t < 64) {
    float a = 0.f, c = 0.f;
#pragma unroll
    for (int i = 0; i < 16; ++i) { a += r1[i][t]; c += r2[i][t]; }
    atomicAdd(&sums[t], a);
    atomicAdd(&sumsq[t], c);
  }
}

// ---------------- K4: BN finalize + exact GELU + transposed write ----------------
__global__ __launch_bounds__(256) void k4_bn(const float* __restrict__ h,
                                             const float* __restrict__ sums,
                                             const float* __restrict__ sumsq,
                                             const float* __restrict__ gamma,
                                             const float* __restrict__ beta,
                                             float* __restrict__ out) {
  __shared__ float tile[64][65];
  const int bid = blockIdx.x;
  const int b = bid >> 6;
  const int n0 = (bid & 63) << 6;
  const int t = threadIdx.x;
  const int o = t & 63;
#pragma unroll
  for (int it = 0; it < 16; ++it) {
    const int n = (t >> 6) * 16 + it;
    tile[n][o] = h[(((size_t)b << 12) + n0 + n) * 64 + o];
  }
  __syncthreads();
  const int j = t & 63;
#pragma unroll
  for (int it = 0; it < 16; ++it) {
    const int oo = (t >> 6) * 16 + it;
    const float mean = sums[oo] * (1.0f / 32768.0f);
    const float var = sumsq[oo] * (1.0f / 32768.0f) - mean * mean;
    const float sc = gamma[oo] / sqrtf(var + 1e-5f);
    const float hv = tile[j][oo];
    const float hn = (hv - mean) * sc + beta[oo];
    const float g = 0.5f * hn * (1.0f + erff(hn * 0.70710678118654752f));
    out[((size_t)(b * 64 + oo)) * 4096 + n0 + j] = g;
  }
}

extern "C" void kernel_launch(void* const* d_in, const int* in_sizes, int n_in,
                              void* d_out, int out_size, void* d_ws, size_t ws_size,
                              hipStream_t stream) {
  const float* x = (const float*)d_in[0];
  const float* w = (const float*)d_in[1];
  const float* gamma = (const float*)d_in[2];
  const float* beta = (const float*)d_in[3];
  float* out = (float*)d_out;

  float* sq_ws = (float*)d_ws;               // 32768
  float* y_ws = sq_ws + 32768;               // 8 MB
  float* delta_ws = y_ws + 2097152;          // 8 MB
  float* h_ws = delta_ws + 2097152;          // 8 MB (k3/k4) — overlaid by xhl in k1/k2
  int* idx_ws = (int*)(h_ws + 2097152);      // 2.6 MB
  float* sums = (float*)(idx_ws + 655360);   // 64
  float* sumsq = sums + 64;                  // 64
  unsigned short* xhl = (unsigned short*)h_ws;  // 8 MB bf16 hi/lo rows (dead after k2)

  hipMemsetAsync(sums, 0, 2 * 64 * sizeof(float), stream);
  k1_pre<<<512, 256, 0, stream>>>(x, w, sq_ws, y_ws, delta_ws, xhl);
  k2_knn<<<512, 256, 0, stream>>>(xhl, sq_ws, idx_ws);
  k3_gather<<<1024, 256, 0, stream>>>(y_ws, delta_ws, idx_ws, h_ws, sums, sumsq);
  k4_bn<<<512, 256, 0, stream>>>(h_ws, sums, sumsq, gamma, beta, out);
}

// Round 7
// 351.725 us; speedup vs baseline: 2.0906x; 1.0694x over previous
//
#include <hip/hip_runtime.h>

#define BIGF 3.402823466e38f

typedef __attribute__((ext_vector_type(8))) short bf16x8;
typedef __attribute__((ext_vector_type(4))) float f32x4;

__device__ __forceinline__ void gload_lds16u(const unsigned short* g, unsigned short* lds) {
  __builtin_amdgcn_global_load_lds((const __attribute__((address_space(1))) void*)g,
                                   (__attribute__((address_space(3))) void*)lds, 16, 0, 0);
}

__device__ __forceinline__ unsigned short bf16_rne(float f) {
  unsigned int u = __float_as_uint(f);
  return (unsigned short)((u + 0x7fffu + ((u >> 16) & 1u)) >> 16);
}

// ---------------- K1: transpose + sq + y + delta + bf16 hi/lo packed rows ----------------
__global__ __launch_bounds__(256) void k1_pre(const float* __restrict__ x, const float* __restrict__ w,
                                              float* __restrict__ sq, float* __restrict__ y,
                                              float* __restrict__ delta, unsigned short* __restrict__ xhl) {
  __shared__ __align__(16) float xt[64][68];
  __shared__ __align__(16) float ws[128][64];
  const int t = threadIdx.x;
  const int bid = blockIdx.x;
  const int b = bid >> 6;
  const int n0 = (bid & 63) << 6;
  const float* xb = x + (size_t)b * 64 * 4096;

#pragma unroll
  for (int rep = 0; rep < 16; ++rep) {
    int id = rep * 256 + t;
    int d = id >> 6, n = id & 63;
    xt[n][d] = xb[(size_t)d * 4096 + n0 + n];
  }
#pragma unroll
  for (int rep = 0; rep < 32; ++rep) {
    int id = rep * 256 + t;
    int u = id >> 6, dd = id & 63;
    ws[u][dd] = w[(u & 63) * 128 + ((u >> 6) << 6) + dd];
  }
  __syncthreads();

  {
    const int p = t >> 2;
    const int cg = t & 3;
    uint4* orow = (uint4*)xhl + ((size_t)(b << 12) + n0 + p) * 16;
#pragma unroll
    for (int cc = 0; cc < 4; ++cc) {
      const int c = cg * 4 + cc;
      const int kb = (c & 7) * 8;
      const bool lohalf = (c >= 8);
      unsigned int pk[4];
#pragma unroll
      for (int j2 = 0; j2 < 4; ++j2) {
        unsigned short u0, u1;
#pragma unroll
        for (int e = 0; e < 2; ++e) {
          const float xv = xt[p][kb + j2 * 2 + e];
          unsigned short h = bf16_rne(xv);
          unsigned short r;
          if (!lohalf) r = h;
          else r = bf16_rne(xv - __uint_as_float(((unsigned int)h) << 16));
          if (e == 0) u0 = r; else u1 = r;
        }
        pk[j2] = (unsigned int)u0 | ((unsigned int)u1 << 16);
      }
      uint4 v;
      v.x = pk[0]; v.y = pk[1]; v.z = pk[2]; v.w = pk[3];
      orow[c ^ (p & 7)] = v;
    }
  }

  const int p = t & 63;
  const int oc = t >> 6;
  float accy[16], accz[16];
#pragma unroll
  for (int j = 0; j < 16; ++j) { accy[j] = 0.f; accz[j] = 0.f; }

#pragma unroll 4
  for (int d4 = 0; d4 < 16; ++d4) {
    const float4 xv = *(const float4*)&xt[p][d4 * 4];
#pragma unroll
    for (int j = 0; j < 16; ++j) {
      const int o = oc * 16 + j;
      const float4 wy = *(const float4*)&ws[o][d4 * 4];
      const float4 wz = *(const float4*)&ws[o + 64][d4 * 4];
      accy[j] = fmaf(xv.x, wy.x, fmaf(xv.y, wy.y, fmaf(xv.z, wy.z, fmaf(xv.w, wy.w, accy[j]))));
      accz[j] = fmaf(xv.x, wz.x, fmaf(xv.y, wz.y, fmaf(xv.z, wz.z, fmaf(xv.w, wz.w, accz[j]))));
    }
  }

  if (oc == 0) {
    float s = 0.f;
#pragma unroll
    for (int d4 = 0; d4 < 16; ++d4) {
      const float4 v = *(const float4*)&xt[p][d4 * 4];
      s = fmaf(v.x, v.x, fmaf(v.y, v.y, fmaf(v.z, v.z, fmaf(v.w, v.w, s))));
    }
    sq[b * 4096 + n0 + p] = s;
  }

  const size_t row = ((size_t)b * 4096 + n0 + p) * 64 + oc * 16;
#pragma unroll
  for (int j4 = 0; j4 < 4; ++j4) {
    float4 yv = make_float4(accy[j4 * 4], accy[j4 * 4 + 1], accy[j4 * 4 + 2], accy[j4 * 4 + 3]);
    float4 dv = make_float4(accz[j4 * 4] - accy[j4 * 4], accz[j4 * 4 + 1] - accy[j4 * 4 + 1],
                            accz[j4 * 4 + 2] - accy[j4 * 4 + 2], accz[j4 * 4 + 3] - accy[j4 * 4 + 3]);
    *(float4*)&y[row + j4 * 4] = yv;
    *(float4*)&delta[row + j4 * 4] = dv;
  }
}

// ---------------- K2: MFMA distance GEMM (bf16 hi/lo) + streaming top-20 ----------------
// Round-3 skeleton (76.8KB LDS, launch_bounds(256,2) — the known spill-free config).
// Changes vs r3: (a) all 8 scan ds_read_b128 issued before processing (latency overlap);
// (b) raw-v accept buffer + push-time threshold tightening via taup=min(taup,max(k18raw,mpraw))
// — 2 regs, 2 VALU/push, provably >= true 20th (19 list elems + any push bound 20 values).
__global__ __launch_bounds__(256, 2) void k2_knn(const unsigned short* __restrict__ xhl,
                                                 const float* __restrict__ sq,
                                                 int* __restrict__ idx_out) {
  __shared__ __align__(16) float smem[4096 + 8192 + 6656];
  const int t = threadIdx.x;
  const int lane = t & 63;
  const int w = t >> 6;
  float* BsW = smem + 4096 + (w << 11);
  uint2* bufL = (uint2*)(smem + 12288) + ((w << 6) + lane) * 13;

  const int bid = blockIdx.x;
  const int b = bid >> 6;
  const int n0 = (bid & 63) << 6;
  const int pn = lane & 15, q = lane >> 4;

  const unsigned short* xr = xhl + ((size_t)(b << 12)) * 128;
  const float* sqb = sq + (b << 12);

  // stage A rows (64 points x 256B = 16KB): 16 x 1KB, 4 per wave
  {
    unsigned short* asu = (unsigned short*)smem;
#pragma unroll
    for (int qq = 0; qq < 4; ++qq) {
      const int kk = w * 4 + qq;
      gload_lds16u(xr + (size_t)n0 * 128 + kk * 512 + lane * 8, asu + kk * 512);
    }
  }
  __syncthreads();

  // n-side fragments, register-resident: per nt: [hi0, hi1, lo0, lo1]
  bf16x8 bfr[4][4];
  {
    const uint4* As4 = (const uint4*)smem;
#pragma unroll
    for (int nt = 0; nt < 4; ++nt)
#pragma unroll
      for (int j = 0; j < 4; ++j)
        bfr[nt][j] = *reinterpret_cast<const bf16x8*>(&As4[((nt << 4) + pn) * 16 + (((j << 2) + q) ^ (pn & 7))]);
  }

  float kd[20];
  int ki[20];
#pragma unroll
  for (int s = 0; s < 20; ++s) { kd[s] = BIGF; ki[s] = -1; }
  const float sqn = sqb[n0 + lane];
  const int myn = lane;
  const int swz = myn & 7;
  int cnt = 0;
  float taup = BIGF;     // gate threshold in raw-v space (v = d2 - sqn)
  float k18raw = BIGF;   // kd[18] - sqn snapshot at drain
  float mpraw = -BIGF;   // max raw v pushed since drain

  auto ins = [&](float vd, int vi) {
#pragma unroll
    for (int s = 0; s < 20; ++s) {
      const float od = kd[s];
      const int oi = ki[s];
      const bool lt = vd < od;
      kd[s] = lt ? vd : od;
      ki[s] = lt ? vi : oi;
      vd = lt ? od : vd;
      vi = lt ? oi : vi;
    }
  };

  auto drain = [&]() {
#pragma unroll 1
    for (int j = 0; j < 12; ++j) {
      if (!__any(j < cnt)) break;
      if (j < cnt) {
        const uint2 e = bufL[j];
        const float dv = sqn + __uint_as_float(e.x);  // raw v -> d2
        if (dv < kd[19]) ins(dv, (int)e.y);
      }
    }
    cnt = 0;
    taup = kd[19] - sqn;
    k18raw = kd[18] - sqn;
    mpraw = -BIGF;
  };

  const f32x4 zero4 = {0.f, 0.f, 0.f, 0.f};
  f32x4 acc[4][2];
#pragma unroll
  for (int nt = 0; nt < 4; ++nt) { acc[nt][0] = zero4; acc[nt][1] = zero4; }

  for (int kt = 0; kt < 32; ++kt) {
    const int mbase = (w + 4 * kt) << 5;
    // stage m rows (32 points x 256B = 8KB): 8 x 1KB
    {
      unsigned short* bsu = (unsigned short*)BsW;
      const unsigned short* src = xr + (size_t)mbase * 128;
#pragma unroll
      for (int k = 0; k < 8; ++k) gload_lds16u(src + k * 512 + lane * 8, bsu + k * 512);
    }
    const f32x4 sqm0 = *(const f32x4*)&sqb[mbase + (q << 2)];
    const f32x4 sqm1 = *(const f32x4*)&sqb[mbase + 16 + (q << 2)];
    __builtin_amdgcn_s_waitcnt(0x0F70);  // vmcnt(0)

#pragma unroll
    for (int mt = 0; mt < 2; ++mt) {
      bf16x8 afr[4];
#pragma unroll
      for (int j = 0; j < 4; ++j)
        afr[j] = *reinterpret_cast<const bf16x8*>(&((const uint4*)BsW)[((mt << 4) + pn) * 16 + (((j << 2) + q) ^ (pn & 7))]);
#pragma unroll
      for (int nt = 0; nt < 4; ++nt) {
        f32x4 a = acc[nt][mt];
        a = __builtin_amdgcn_mfma_f32_16x16x32_bf16(afr[0], bfr[nt][0], a, 0, 0, 0);  // hi_m*hi_n
        a = __builtin_amdgcn_mfma_f32_16x16x32_bf16(afr[1], bfr[nt][1], a, 0, 0, 0);
        a = __builtin_amdgcn_mfma_f32_16x16x32_bf16(afr[0], bfr[nt][2], a, 0, 0, 0);  // hi_m*lo_n
        a = __builtin_amdgcn_mfma_f32_16x16x32_bf16(afr[1], bfr[nt][3], a, 0, 0, 0);
        a = __builtin_amdgcn_mfma_f32_16x16x32_bf16(afr[2], bfr[nt][0], a, 0, 0, 0);  // lo_m*hi_n
        a = __builtin_amdgcn_mfma_f32_16x16x32_bf16(afr[3], bfr[nt][1], a, 0, 0, 0);
        acc[nt][mt] = a;
      }
    }

    // dump: value = sq_m - 2*dot, row n, m-quad g=(mt*4+q) at chunk g^(n&7)
#pragma unroll
    for (int nt = 0; nt < 4; ++nt) {
#pragma unroll
      for (int mt = 0; mt < 2; ++mt) {
        const int n = (nt << 4) + pn;
        const int g = (mt << 2) + q;
        const int pc = g ^ (n & 7);
        const f32x4 sv = mt ? sqm1 : sqm0;
        f32x4 dv = sv - 2.0f * acc[nt][mt];
        *(f32x4*)&BsW[(n << 5) + (pc << 2)] = dv;
        acc[nt][mt] = zero4;
      }
    }

    // scan own row (myn): issue ALL 8 chunk loads first (latency overlap), then process.
    float4 vv[8];
#pragma unroll
    for (int cc = 0; cc < 8; ++cc)
      vv[cc] = *(const float4*)&BsW[(myn << 5) + ((cc ^ swz) << 2)];

#pragma unroll
    for (int cc = 0; cc < 8; ++cc) {
      const float4 v = vv[cc];
      const int mb = mbase + (cc << 2);
      const float mn = fminf(fminf(v.x, v.y), fminf(v.z, v.w));
      if (mn < taup) {
        if (v.x < taup) { bufL[cnt] = make_uint2(__float_as_uint(v.x), (unsigned)mb); cnt++; mpraw = fmaxf(mpraw, v.x); }
        if (v.y < taup) { bufL[cnt] = make_uint2(__float_as_uint(v.y), (unsigned)(mb + 1)); cnt++; mpraw = fmaxf(mpraw, v.y); }
        if (v.z < taup) { bufL[cnt] = make_uint2(__float_as_uint(v.z), (unsigned)(mb + 2)); cnt++; mpraw = fmaxf(mpraw, v.z); }
        if (v.w < taup) { bufL[cnt] = make_uint2(__float_as_uint(v.w), (unsigned)(mb + 3)); cnt++; mpraw = fmaxf(mpraw, v.w); }
        taup = fminf(taup, fmaxf(k18raw, mpraw));  // valid whenever >=1 push is buffered
      }
      if (__any(cnt > 8)) drain();
    }
  }
  drain();

  // merge the 4 waves' partial lists (LDS overlay on smem)
  __syncthreads();
  float* pf = smem;                 // [4][20][64]
  int* pi = (int*)(smem + 5120);    // [4][20][64]
#pragma unroll
  for (int s = 0; s < 20; ++s) {
    pf[(w * 20 + s) * 64 + lane] = kd[s];
    pi[(w * 20 + s) * 64 + lane] = ki[s];
  }
  __syncthreads();
  if (w == 0) {
    auto insTie = [&](float vd, int vi) {
#pragma unroll
      for (int s = 0; s < 20; ++s) {
        const float od = kd[s];
        const int oi = ki[s];
        const bool lt = (vd < od) || (vd == od && vi < oi);
        kd[s] = lt ? vd : od;
        ki[s] = lt ? vi : oi;
        vd = lt ? od : vd;
        vi = lt ? oi : vi;
      }
    };
    for (int ww = 1; ww < 4; ++ww) {
#pragma unroll 1
      for (int s = 0; s < 20; ++s) {
        const float dv = pf[(ww * 20 + s) * 64 + lane];
        const int iv = pi[(ww * 20 + s) * 64 + lane];
        if (dv < kd[19] || (dv == kd[19] && iv < ki[19])) insTie(dv, iv);
      }
    }
    int* orow = idx_out + ((size_t)(b << 12) + n0 + lane) * 20;
#pragma unroll
    for (int s = 0; s < 20; ++s) orow[s] = ki[s];
  }
}

// ---------------- K3: gathered neighbor max (float4) + h + BN stats ----------------
__global__ __launch_bounds__(256) void k3_gather(const float* __restrict__ y,
                                                 const float* __restrict__ delta,
                                                 const int* __restrict__ idx,
                                                 float* __restrict__ h,
                                                 float* __restrict__ sums,
                                                 float* __restrict__ sumsq) {
  __shared__ float r1[16][64], r2[16][64];
  const int t = threadIdx.x;
  const int cg = t & 15;   // channels 4cg..4cg+3
  const int pw = t >> 4;   // 16 point-slots
  const int blk = blockIdx.x;  // 1024 blocks x 32 points
  float4 s1 = make_float4(0.f, 0.f, 0.f, 0.f), s2 = s1;
#pragma unroll 1
  for (int pp = 0; pp < 2; ++pp) {
    const int ng = blk * 32 + pp * 16 + pw;
    const int b = ng >> 12;
    const int* row = idx + (size_t)ng * 20;
    float4 mx = make_float4(-BIGF, -BIGF, -BIGF, -BIGF);
#pragma unroll
    for (int kk = 0; kk < 20; ++kk) {
      const int nbr = row[kk];
      const float4 v = *(const float4*)&y[(((size_t)(b << 12)) + nbr) * 64 + cg * 4];
      mx.x = fmaxf(mx.x, v.x); mx.y = fmaxf(mx.y, v.y);
      mx.z = fmaxf(mx.z, v.z); mx.w = fmaxf(mx.w, v.w);
    }
    const float4 dl = *(const float4*)&delta[(size_t)ng * 64 + cg * 4];
    float4 hv = make_float4(mx.x + dl.x, mx.y + dl.y, mx.z + dl.z, mx.w + dl.w);
    *(float4*)&h[(size_t)ng * 64 + cg * 4] = hv;
    s1.x += hv.x; s1.y += hv.y; s1.z += hv.z; s1.w += hv.w;
    s2.x += hv.x * hv.x; s2.y += hv.y * hv.y; s2.z += hv.z * hv.z; s2.w += hv.w * hv.w;
  }
  *(float4*)&r1[pw][cg * 4] = s1;
  *(float4*)&r2[pw][cg * 4] = s2;
  __syncthreads();
  if (t < 64) {
    float a = 0.f, c = 0.f;
#pragma unroll
    for (int i = 0; i < 16; ++i) { a += r1[i][t]; c += r2[i][t]; }
    atomicAdd(&sums[t], a);
    atomicAdd(&sumsq[t], c);
  }
}

// ---------------- K4: BN finalize + exact GELU + transposed write ----------------
__global__ __launch_bounds__(256) void k4_bn(const float* __restrict__ h,
                                             const float* __restrict__ sums,
                                             const float* __restrict__ sumsq,
                                             const float* __restrict__ gamma,
                                             const float* __restrict__ beta,
                                             float* __restrict__ out) {
  __shared__ float tile[64][65];
  const int bid = blockIdx.x;
  const int b = bid >> 6;
  const int n0 = (bid & 63) << 6;
  const int t = threadIdx.x;
  const int o = t & 63;
#pragma unroll
  for (int it = 0; it < 16; ++it) {
    const int n = (t >> 6) * 16 + it;
    tile[n][o] = h[(((size_t)b << 12) + n0 + n) * 64 + o];
  }
  __syncthreads();
  const int j = t & 63;
#pragma unroll
  for (int it = 0; it < 16; ++it) {
    const int oo = (t >> 6) * 16 + it;
    const float mean = sums[oo] * (1.0f / 32768.0f);
    const float var = sumsq[oo] * (1.0f / 32768.0f) - mean * mean;
    const float sc = gamma[oo] / sqrtf(var + 1e-5f);
    const float hv = tile[j][oo];
    const float hn = (hv - mean) * sc + beta[oo];
    const float g = 0.5f * hn * (1.0f + erff(hn * 0.70710678118654752f));
    out[((size_t)(b * 64 + oo)) * 4096 + n0 + j] = g;
  }
}

extern "C" void kernel_launch(void* const* d_in, const int* in_sizes, int n_in,
                              void* d_out, int out_size, void* d_ws, size_t ws_size,
                              hipStream_t stream) {
  const float* x = (const float*)d_in[0];
  const float* w = (const float*)d_in[1];
  const float* gamma = (const float*)d_in[2];
  const float* beta = (const float*)d_in[3];
  float* out = (float*)d_out;

  float* sq_ws = (float*)d_ws;               // 32768
  float* y_ws = sq_ws + 32768;               // 8 MB
  float* delta_ws = y_ws + 2097152;          // 8 MB
  float* h_ws = delta_ws + 2097152;          // 8 MB (k3/k4) — overlaid by xhl in k1/k2
  int* idx_ws = (int*)(h_ws + 2097152);      // 2.6 MB
  float* sums = (float*)(idx_ws + 655360);   // 64
  float* sumsq = sums + 64;                  // 64
  unsigned short* xhl = (unsigned short*)h_ws;  // 8 MB bf16 hi/lo rows (dead after k2)

  hipMemsetAsync(sums, 0, 2 * 64 * sizeof(float), stream);
  k1_pre<<<512, 256, 0, stream>>>(x, w, sq_ws, y_ws, delta_ws, xhl);
  k2_knn<<<512, 256, 0, stream>>>(xhl, sq_ws, idx_ws);
  k3_gather<<<1024, 256, 0, stream>>>(y_ws, delta_ws, idx_ws, h_ws, sums, sumsq);
  k4_bn<<<512, 256, 0, stream>>>(h_ws, sums, sumsq, gamma, beta, out);
}